// Round 1
// 342.963 us; speedup vs baseline: 1.0064x; 1.0064x over previous
//
#include <hip/hip_runtime.h>
#include <stdint.h>

// B=8192, E=16, C=256, K=2, H=64, OUT=387
// h = relu(const_h + brelu + lap @ (x_b @ W1)), out = h @ fc_w^T + fc_b
// Round-4: amortize B-operand fragment loads across the block.
//  - w1t2 staged once per block into LDS (32KB); phase-B' frag reads are
//    conflict-free ds_read_b128 instead of per-wave L2 reloads (268->67 MB).
//  - Phase D is block-cooperative: 25 o-tiles split 7/6/6/6 across waves,
//    each wave computes all 4 batches from hs (fcw2 L2 traffic 410->102 MB).
//    Cross-wave hs handoff via lgkmcnt(0)+s_barrier (vmcnt prefetch stays live).
//  - hs pad 72->80 shorts: ha ds_read_b128 bank conflict 8-way -> 4-way.

typedef __attribute__((ext_vector_type(4))) float f32x4;
typedef __attribute__((ext_vector_type(8))) short s16x8;
typedef __attribute__((ext_vector_type(4))) short s16x4;

// workspace byte offsets
#define WS_CH_B    0       // 64 f32: colsum(even cheb rows) + brelu_bias
#define WS_LAP_B   256     // 256 f32: fp32 laplacian (fallback path)
#define WS_LAPA_B  1280    // 64*4 bf16: lap as 16x16x16 A-fragments
#define WS_FCB_B   1792    // 400 f32: fc_b zero-padded
#define WS_W1T2_B  4096    // 32 frags * 512 shorts: W1 B-frags, frag=(kb*4+nt)
#define WS_FCW2_B  36864   // 50 frags * 512 shorts: fc_w B-frags, frag=(tt*2+f)

static __device__ __forceinline__ short f2bf(float f) {
    union { float f; uint32_t u; } v; v.f = f;
    uint32_t r = (v.u + 0x7fffu + ((v.u >> 16) & 1u)) >> 16;  // RNE
    return (short)r;
}

__global__ void prep_kernel(const float* __restrict__ adj,
                            const float* __restrict__ adj_bias,
                            const float* __restrict__ cheb_w,
                            const float* __restrict__ brelu_bias,
                            const float* __restrict__ fc_w,
                            const float* __restrict__ fc_b,
                            char* __restrict__ ws) {
    float* chf  = (float*)(ws + WS_CH_B);
    float* lapf = (float*)(ws + WS_LAP_B);
    short* lapA = (short*)(ws + WS_LAPA_B);
    float* fcbp = (float*)(ws + WS_FCB_B);
    short* w1t2 = (short*)(ws + WS_W1T2_B);
    short* fcw2 = (short*)(ws + WS_FCW2_B);
    int t = threadIdx.x;

    if (blockIdx.x == 0) {
        __shared__ float sw[16][17];
        __shared__ float sdre[16];
        __shared__ float slap[16][16];
        __shared__ float csum[4][64];
        float ab = adj_bias[0];
        {
            int i = t >> 4, j = t & 15;
            sw[i][j] = fmaxf(adj[t] + ab, 0.f);
        }
        {   // colsum of even cheb rows, parallel over 256 threads
            int hh = t & 63, part = t >> 6;
            float s = 0.f;
            #pragma unroll 8
            for (int i = 0; i < 64; ++i) s += cheb_w[(2 * (part * 64 + i)) * 64 + hh];
            csum[part][hh] = s;
        }
        __syncthreads();
        if (t < 16) {
            float s = 0.f;
            #pragma unroll
            for (int j = 0; j < 16; ++j) s += sw[t][j];
            sdre[t] = 1.0f / sqrtf(s + 1e-5f);
        }
        __syncthreads();
        {
            int i = t >> 4, j = t & 15;
            float l = (i == j ? 1.f : 0.f) - sdre[i] * sw[i][j] * sdre[j];
            slap[i][j] = l;
            lapf[t] = l;
        }
        __syncthreads();
        if (t < 64) {
            int m = t & 15, qq = t >> 4;
            #pragma unroll
            for (int i = 0; i < 4; ++i)
                lapA[t * 4 + i] = f2bf(slap[m][qq * 4 + i]);  // A[m][k=qq*4+i]
            chf[t] = csum[0][t] + csum[1][t] + csum[2][t] + csum[3][t] + brelu_bias[t];
        }
        for (int o = t; o < 400; o += 256) fcbp[o] = (o < 387) ? fc_b[o] : 0.f;
    }
    int gt = blockIdx.x * blockDim.x + t;
    int nthr = gridDim.x * blockDim.x;
    // W1 B-fragments: frag=(kb*4+nt), element = frag*512 + lane*8 + j
    //   B[k = kb*32 + (lane>>4)*8 + j][col = nt*16 + (lane&15)], W1[c][h]=cheb_w[2c+1][h]
    for (int idx = gt; idx < 32 * 512; idx += nthr) {
        int frag = idx >> 9, r = idx & 511;
        int lane = r >> 3, j = r & 7;
        int kb = frag >> 2, nt = frag & 3;
        int k = kb * 32 + (lane >> 4) * 8 + j;
        int col = nt * 16 + (lane & 15);
        w1t2[idx] = f2bf(cheb_w[(2 * k + 1) * 64 + col]);
    }
    // fc_w B-fragments: frag=(tt*2+f), element = frag*512 + lane*8 + j
    //   B[k = f*32 + (lane>>4)*8 + j][o = tt*16 + (lane&15)], fc_w[o][k]
    for (int idx = gt; idx < 50 * 512; idx += nthr) {
        int frag = idx >> 9, r = idx & 511;
        int lane = r >> 3, j = r & 7;
        int tt = frag >> 1, f = frag & 1;
        int o = tt * 16 + (lane & 15);
        int k = f * 32 + (lane >> 4) * 8 + j;
        fcw2[idx] = (o < 387) ? f2bf(fc_w[o * 64 + k]) : (short)0;
    }
}

__global__ __launch_bounds__(256) void fused_kernel(
        const float* __restrict__ x,
        const char* __restrict__ ws,
        float* __restrict__ out) {
    const float* chf  = (const float*)(ws + WS_CH_B);
    const short* lapA = (const short*)(ws + WS_LAPA_B);
    const float* fcbp = (const float*)(ws + WS_FCB_B);
    const short* w1t2 = (const short*)(ws + WS_W1T2_B);
    const short* fcw2 = (const short*)(ws + WS_FCW2_B);

    __shared__ __align__(16) short sw1[32 * 512];   // 32KB: W1 B-frags (block-shared)
    __shared__ __align__(16) short hs[4][16][80];   // bf16 h per batch, +16 pad (4-way banks, 16B-aligned rows)

    const int lane = threadIdx.x & 63;
    const int wave = threadIdx.x >> 6;
    const int n = lane & 15;   // MFMA col (B/C) == A row m
    const int q = lane >> 4;   // quad
    const long b = (long)blockIdx.x * 4 + wave;   // one batch per wave (phases B'/C)

    // ---- stage W1 B-frags into LDS, once per block (cuts per-wave L2 reloads 4x)
    {
        const s16x8* srcv = (const s16x8*)w1t2;
        s16x8* dstv = (s16x8*)sw1;
        #pragma unroll
        for (int i = 0; i < 8; ++i)
            dstv[i * 256 + threadIdx.x] = srcv[i * 256 + threadIdx.x];
    }

    // ---- Phase B': g = bf16(x_b) @ W1   (M=16 rows, N=64 hh, K=256 c)
    const float* xrow = x + b * 4096 + n * 256 + q * 8;
    f32x4 xr[16];
    #pragma unroll
    for (int kb = 0; kb < 8; ++kb) {
        xr[2 * kb]     = *(const f32x4*)(xrow + kb * 32);
        xr[2 * kb + 1] = *(const f32x4*)(xrow + kb * 32 + 4);
    }
    s16x8 af[8];
    #pragma unroll
    for (int kb = 0; kb < 8; ++kb) {
        f32x4 xa = xr[2 * kb], xc = xr[2 * kb + 1];
        af[kb][0] = f2bf(xa[0]); af[kb][1] = f2bf(xa[1]);
        af[kb][2] = f2bf(xa[2]); af[kb][3] = f2bf(xa[3]);
        af[kb][4] = f2bf(xc[0]); af[kb][5] = f2bf(xc[1]);
        af[kb][6] = f2bf(xc[2]); af[kb][7] = f2bf(xc[3]);
    }
    __syncthreads();   // sw1 staged & visible

    // dense fragment loads from LDS, 1-ahead pipeline
    const short* w1l = sw1 + lane * 8;
    s16x8 bfr[2][4];
    #pragma unroll
    for (int nt = 0; nt < 4; ++nt)
        bfr[0][nt] = *(const s16x8*)(w1l + nt * 512);
    f32x4 g[4];
    #pragma unroll
    for (int nt = 0; nt < 4; ++nt) g[nt] = (f32x4){0.f, 0.f, 0.f, 0.f};
    #pragma unroll
    for (int kb = 0; kb < 8; ++kb) {
        const int cur = kb & 1;
        if (kb < 7) {
            #pragma unroll
            for (int nt = 0; nt < 4; ++nt)
                bfr[cur ^ 1][nt] = *(const s16x8*)(w1l + ((kb + 1) * 4 + nt) * 512);
        }
        #pragma unroll
        for (int nt = 0; nt < 4; ++nt)
            g[nt] = __builtin_amdgcn_mfma_f32_16x16x32_bf16(af[kb], bfr[cur][nt], g[nt], 0, 0, 0);
    }

    // ---- Phase C': h = lap @ g  (K=16). g's C-layout == 16x16x16 B-layout.
    f32x4 h[4];
#if defined(__has_builtin) && __has_builtin(__builtin_amdgcn_mfma_f32_16x16x16bf16_1k)
    {
        s16x4 la = *(const s16x4*)(lapA + lane * 4);
        const f32x4 z4 = (f32x4){0.f, 0.f, 0.f, 0.f};
        #pragma unroll
        for (int nt = 0; nt < 4; ++nt) {
            s16x4 gb;
            gb[0] = f2bf(g[nt][0]); gb[1] = f2bf(g[nt][1]);
            gb[2] = f2bf(g[nt][2]); gb[3] = f2bf(g[nt][3]);
            h[nt] = __builtin_amdgcn_mfma_f32_16x16x16bf16_1k(la, gb, z4, 0, 0, 0);
        }
    }
#else
    {
        __shared__ float gs[4][16][68];
        const float* lapf = (const float*)(ws + WS_LAP_B);
        #pragma unroll
        for (int r = 0; r < 4; ++r) {
            gs[wave][q * 4 + r][0 * 16 + n] = g[0][r];
            gs[wave][q * 4 + r][1 * 16 + n] = g[1][r];
            gs[wave][q * 4 + r][2 * 16 + n] = g[2][r];
            gs[wave][q * 4 + r][3 * 16 + n] = g[3][r];
        }
        __syncthreads();
        #pragma unroll
        for (int nt = 0; nt < 4; ++nt) h[nt] = (f32x4){0.f, 0.f, 0.f, 0.f};
        #pragma unroll
        for (int e = 0; e < 16; ++e) {
            float l0 = lapf[(q * 4 + 0) * 16 + e];
            float l1 = lapf[(q * 4 + 1) * 16 + e];
            float l2 = lapf[(q * 4 + 2) * 16 + e];
            float l3 = lapf[(q * 4 + 3) * 16 + e];
            #pragma unroll
            for (int nt = 0; nt < 4; ++nt) {
                float gv = gs[wave][e][nt * 16 + n];
                h[nt][0] += l0 * gv; h[nt][1] += l1 * gv;
                h[nt][2] += l2 * gv; h[nt][3] += l3 * gv;
            }
        }
    }
#endif

    // ---- relu(+const) epilogue -> bf16 -> LDS (A-operand layout for phase D)
    #pragma unroll
    for (int nt = 0; nt < 4; ++nt) {
        float cv = chf[nt * 16 + n];
        #pragma unroll
        for (int r = 0; r < 4; ++r) {
            float v = fmaxf(h[nt][r] + cv, 0.f);
            hs[wave][q * 4 + r][nt * 16 + n] = f2bf(v);
        }
    }

    // ---- Phase D (block-cooperative): out = h @ fc_w^T  (M=64 rows = 4 batches, N=387, K=64)
    // 25 o-tiles split across the 4 waves: wave w owns tt = w, w+4, ... (7/6/6/6).
    // Issue first B-frag prefetch BEFORE the barrier; cross the barrier with
    // lgkmcnt(0) only so the vmcnt prefetch stays in flight.
    const short* fw = fcw2 + lane * 8;
    s16x8 fb[2][2];
    {
        const int tt0 = wave;
        fb[0][0] = *(const s16x8*)(fw + (tt0 * 2 + 0) * 512);
        fb[0][1] = *(const s16x8*)(fw + (tt0 * 2 + 1) * 512);
    }
    asm volatile("s_waitcnt lgkmcnt(0)" ::: "memory");  // hs writes drained
    __builtin_amdgcn_s_barrier();                       // all 4 batches' hs ready
    __builtin_amdgcn_sched_barrier(0);                  // no code motion across barrier

    // A-frags for all 4 batches (LDS, reused across all owned o-tiles)
    s16x8 ha[4][2];
    #pragma unroll
    for (int gi = 0; gi < 4; ++gi) {
        ha[gi][0] = *(const s16x8*)(&hs[gi][n][q * 8]);
        ha[gi][1] = *(const s16x8*)(&hs[gi][n][32 + q * 8]);
    }

    const long bbase = (long)blockIdx.x * 4;
    #pragma unroll
    for (int i = 0; i < 7; ++i) {
        const int tt = wave + 4 * i;
        if (tt >= 25) break;
        const int cur = i & 1;
        const int tn = tt + 4;
        if (tn < 25) {
            fb[cur ^ 1][0] = *(const s16x8*)(fw + (tn * 2 + 0) * 512);
            fb[cur ^ 1][1] = *(const s16x8*)(fw + (tn * 2 + 1) * 512);
        }
        const int o = tt * 16 + n;
        const float bias = fcbp[o];
        #pragma unroll
        for (int gi = 0; gi < 4; ++gi) {
            f32x4 acc = (f32x4){bias, bias, bias, bias};
            acc = __builtin_amdgcn_mfma_f32_16x16x32_bf16(ha[gi][0], fb[cur][0], acc, 0, 0, 0);
            acc = __builtin_amdgcn_mfma_f32_16x16x32_bf16(ha[gi][1], fb[cur][1], acc, 0, 0, 0);
            if (o < 387) {
                float* outb = out + ((bbase + gi) * 16 + q * 4) * 387;
                outb[0 * 387 + o] = acc[0];
                outb[1 * 387 + o] = acc[1];
                outb[2 * 387 + o] = acc[2];
                outb[3 * 387 + o] = acc[3];
            }
        }
    }
}

extern "C" void kernel_launch(void* const* d_in, const int* in_sizes, int n_in,
                              void* d_out, int out_size, void* d_ws, size_t ws_size,
                              hipStream_t stream) {
    const float* x          = (const float*)d_in[0];
    const float* adj        = (const float*)d_in[1];
    const float* adj_bias   = (const float*)d_in[2];
    const float* cheb_w     = (const float*)d_in[3];
    const float* brelu_bias = (const float*)d_in[4];
    const float* fc_w       = (const float*)d_in[5];
    const float* fc_b       = (const float*)d_in[6];
    float* outp = (float*)d_out;
    char* ws = (char*)d_ws;

    prep_kernel<<<64, 256, 0, stream>>>(adj, adj_bias, cheb_w, brelu_bias, fc_w, fc_b, ws);
    fused_kernel<<<2048, 256, 0, stream>>>(x, ws, outp);
}